// Round 11
// baseline (576.906 us; speedup 1.0000x reference)
//
#include <hip/hip_runtime.h>

typedef unsigned short u16;
typedef unsigned int u32;

typedef __bf16 bf16x8 __attribute__((ext_vector_type(8)));
typedef float f32x4 __attribute__((ext_vector_type(4)));

#define OUT_F 4096
#define IN_F 4096
#define M_ROWS 4096              // 2 * 2048
#define NUM_GROUPS ((OUT_F * IN_F) / 32)   // 524288

// ---------- helpers ----------

__device__ __forceinline__ u16 f2bf(float f) {
    union { float f; u32 u; } c; c.f = f;
    u32 u = c.u;
    u += 0x7fffu + ((u >> 16) & 1u);   // round-to-nearest-even (finite inputs)
    return (u16)(u >> 16);
}

__device__ __forceinline__ u32 pk2(float a, float b) {
    return (u32)f2bf(a) | ((u32)f2bf(b) << 16);
}

// async global -> LDS, 16 bytes per lane (global_load_lds_dwordx4)
__device__ __forceinline__ void async_copy16(const u16* g, u16* l) {
    __builtin_amdgcn_global_load_lds(
        (const __attribute__((address_space(1))) u32*)g,
        (__attribute__((address_space(3))) u32*)l,
        16, 0, 0);
}

// 32-bit LDS byte address for inline-asm ds_read
__device__ __forceinline__ u32 lds_addr(const u16* p) {
    return (u32)(uintptr_t)(const __attribute__((address_space(3))) u16*)p;
}

// ---------- fused prep (unchanged — HBM floor ~25us) ----------
__global__ __launch_bounds__(256) void prep_kernel(
        const float* __restrict__ x, const int* __restrict__ q,
        const float* __restrict__ scales,
        u16* __restrict__ W, u16* __restrict__ Xb) {
    int bid = blockIdx.x;
    int tid = threadIdx.x;
    if (bid < 8192) {
        int t = bid * 256 + tid;                 // [0, NUM_TRIPLETS)
        int b0 = q[3 * t];
        int b1 = q[3 * t + 1];
        int b2 = q[3 * t + 2];
        float mv = scales[t >> 2];
        float s = mv * (2.0f / 7.0f);            // w = v*s - mv
        float o = -mv;

        int v0 = b0 & 7;
        int v1 = (b0 >> 3) & 7;
        int v2 = ((b0 >> 6) & 3) | ((b1 & 1) << 2);
        int v3 = (b1 >> 1) & 7;
        int v4 = (b1 >> 4) & 7;
        int v5 = ((b1 >> 7) & 1) | ((b2 & 3) << 1);
        int v6 = (b2 >> 2) & 7;
        int v7 = (b2 >> 5) & 7;
        uint4 w;
        w.x = pk2(fmaf((float)v0, s, o), fmaf((float)v1, s, o));
        w.y = pk2(fmaf((float)v2, s, o), fmaf((float)v3, s, o));
        w.z = pk2(fmaf((float)v4, s, o), fmaf((float)v5, s, o));
        w.w = pk2(fmaf((float)v6, s, o), fmaf((float)v7, s, o));
        ((uint4*)W)[t] = w;
    } else {
        int i = (bid - 8192) * 256 + tid;
        const float4* p = (const float4*)x + (size_t)i * 2;
        float4 u = p[0], v = p[1];
        uint4 w;
        w.x = pk2(u.x, u.y);
        w.y = pk2(u.z, u.w);
        w.z = pk2(v.x, v.y);
        w.w = pk2(v.z, v.w);
        ((uint4*)Xb)[i] = w;
    }
}

// ---------- 256x128 tile, 2 waves of 128x128, fat-wave bf16 GEMM ----------
// C[m][n] = sum_k A[m][k]*B[n][k] + bias[n]
//
// R2..R10 post-mortem: seven schedule variants pinned at ~4300 cyc/tile-pair
// (MFMA 2483 + port 2688, ~35% overlap); scheduling is exhausted. R11 cuts
// the only untouched quantity: FRAGMENT REDUNDANCY. 4 waves x (128x64) read
// each unique LDS byte 2x (96 KB/block-tile). 2 waves x (128x128) read it
// 1.33x (64 KB) — port demand 2688 -> 1920 cyc, below the MFMA floor.
// Cost: acc 256 + frags 48 VGPR (~330/wave, no-spill<450, launch_bounds
// (128,1)); occupancy 4 waves/CU (1/SIMD) — in-wave ILP (8 indep acc rows,
// counted-lgkm ladder) does the hiding. MFMA count/geometry per CU unchanged.
// Staging offsets are stride-uniform (chunk-XOR is tid-only for 16-row
// passes): 24 passes, 2 address registers.
__global__ __launch_bounds__(128, 1) void gemm_bt_kernel(
        const u16* __restrict__ A, const u16* __restrict__ B,
        const float* __restrict__ bias, float* __restrict__ C) {
    __shared__ u16 sA[256 * 64];    // 32 KB
    __shared__ u16 sB[128 * 64];    // 16 KB

    const int tid = threadIdx.x;
    const int lane = tid & 63;
    const int wr = tid >> 6;         // wave 0..1 -> rows wr*128 + [0,128)
    const int ln = lane & 15;
    const int quad = lane >> 4;
    const int lnx = ln & 7;

    // XCD-aware bijective swizzle: 512 blocks, 8 XCDs, 64 contiguous/XCD.
    const int lin = blockIdx.x;
    const int wg = (lin & 7) * 64 + (lin >> 3);
    const int mb = (wg >> 5) * 256;   // M tile (16)
    const int nb = (wg & 31) * 128;   // N tile (32)

    // staging: pass p covers rows [p*16, p*16+16), 8 chunks each.
    // slot s = p*128+tid: row = p*16 + (tid>>3), phys chunk = tid&7,
    // logical = pc ^ (row&7); row&7 = (tid>>3)&7 (p*16 = 0 mod 8) -> tid-only.
    const int gRow = tid >> 3;
    const int gOff0 = gRow * IN_F + (((tid & 7) ^ (gRow & 7)) * 8);
    const int ldsSlot = tid * 8;     // u16 offset; + p*1024 per pass
    const u16* baseA = A + (size_t)mb * IN_F;
    const u16* baseB = B + (size_t)nb * IN_F;

    auto STAGE_A = [&](int ko) {
#pragma unroll
        for (int p = 0; p < 16; ++p)
            async_copy16(baseA + gOff0 + p * (16 * IN_F) + ko,
                         &sA[ldsSlot + p * 1024]);
    };
    auto STAGE_B = [&](int ko) {
#pragma unroll
        for (int p = 0; p < 8; ++p)
            async_copy16(baseB + gOff0 + p * (16 * IN_F) + ko,
                         &sB[ldsSlot + p * 1024]);
    };

    // fragment read bases (bytes). Row stride 128 B; imm = frag*2048.
    const u32 sAb = lds_addr(sA);
    const u32 sBb = lds_addr(sB);
    const u32 aB0 = sAb + (u32)((wr * 128 + ln) * 128 + ((quad ^ lnx) * 16));
    const u32 aB1 = sAb + (u32)((wr * 128 + ln) * 128 + (((4 + quad) ^ lnx) * 16));
    const u32 bB0 = sBb + (u32)(ln * 128 + ((quad ^ lnx) * 16));
    const u32 bB1 = sBb + (u32)(ln * 128 + (((4 + quad) ^ lnx) * 16));

    // bias for this thread's 8 output column groups
    float bj[8];
#pragma unroll
    for (int j = 0; j < 8; ++j)
        bj[j] = bias[nb + j * 16 + ln];

    f32x4 acc[8][8];
#pragma unroll
    for (int i = 0; i < 8; ++i)
#pragma unroll
        for (int j = 0; j < 8; ++j) acc[i][j] = (f32x4)0.0f;

    bf16x8 av[4][2];     // A fragments, 4 rows at a time (reused)
    bf16x8 bv[8][2];     // B fragments, all 8 col-groups live whole tile

#define DSR(dst, base, IMM) \
    asm volatile("ds_read_b128 %0, %1 offset:" #IMM \
                 : "=v"(dst) : "v"(base))

#define WAITG(N) \
    asm volatile("s_waitcnt lgkmcnt(" #N ")"); \
    __builtin_amdgcn_sched_barrier(0);

// av[AI] x bv[JB..JB+3] -> acc[ACR][JB..JB+3]; kk0 sweep then kk1 sweep
// (same-acc dep distance 4)
#define MQ(AI, ACR, JB) \
    acc[ACR][(JB)+0] = __builtin_amdgcn_mfma_f32_16x16x32_bf16( \
        av[AI][0], bv[(JB)+0][0], acc[ACR][(JB)+0], 0, 0, 0); \
    acc[ACR][(JB)+1] = __builtin_amdgcn_mfma_f32_16x16x32_bf16( \
        av[AI][0], bv[(JB)+1][0], acc[ACR][(JB)+1], 0, 0, 0); \
    acc[ACR][(JB)+2] = __builtin_amdgcn_mfma_f32_16x16x32_bf16( \
        av[AI][0], bv[(JB)+2][0], acc[ACR][(JB)+2], 0, 0, 0); \
    acc[ACR][(JB)+3] = __builtin_amdgcn_mfma_f32_16x16x32_bf16( \
        av[AI][0], bv[(JB)+3][0], acc[ACR][(JB)+3], 0, 0, 0); \
    acc[ACR][(JB)+0] = __builtin_amdgcn_mfma_f32_16x16x32_bf16( \
        av[AI][1], bv[(JB)+0][1], acc[ACR][(JB)+0], 0, 0, 0); \
    acc[ACR][(JB)+1] = __builtin_amdgcn_mfma_f32_16x16x32_bf16( \
        av[AI][1], bv[(JB)+1][1], acc[ACR][(JB)+1], 0, 0, 0); \
    acc[ACR][(JB)+2] = __builtin_amdgcn_mfma_f32_16x16x32_bf16( \
        av[AI][1], bv[(JB)+2][1], acc[ACR][(JB)+2], 0, 0, 0); \
    acc[ACR][(JB)+3] = __builtin_amdgcn_mfma_f32_16x16x32_bf16( \
        av[AI][1], bv[(JB)+3][1], acc[ACR][(JB)+3], 0, 0, 0);

    // ---- prologue: stage tile 0, drain, publish ----
    STAGE_A(0);
    STAGE_B(0);
    asm volatile("s_waitcnt vmcnt(0)");
    __builtin_amdgcn_s_barrier();

    // ---- dephase: half of each co-resident pair starts ~2176 cyc late ----
    if ((lin ^ (lin >> 8)) & 1) {
        asm volatile("s_sleep 34");
    }

#pragma unroll 1
    for (int t = 0; t < 64; ++t) {
        // ---- reads: bv0-3 (8), av rows0-3 (8), bv4-7 (8) = 24 in order ----
        DSR(bv[0][0], bB0, 0);     DSR(bv[0][1], bB1, 0);
        DSR(bv[1][0], bB0, 2048);  DSR(bv[1][1], bB1, 2048);
        DSR(bv[2][0], bB0, 4096);  DSR(bv[2][1], bB1, 4096);
        DSR(bv[3][0], bB0, 6144);  DSR(bv[3][1], bB1, 6144);
        DSR(av[0][0], aB0, 0);     DSR(av[0][1], aB1, 0);
        DSR(av[1][0], aB0, 2048);  DSR(av[1][1], aB1, 2048);
        DSR(av[2][0], aB0, 4096);  DSR(av[2][1], aB1, 4096);
        DSR(av[3][0], aB0, 6144);  DSR(av[3][1], aB1, 6144);
        DSR(bv[4][0], bB0, 8192);  DSR(bv[4][1], bB1, 8192);
        DSR(bv[5][0], bB0, 10240); DSR(bv[5][1], bB1, 10240);
        DSR(bv[6][0], bB0, 12288); DSR(bv[6][1], bB1, 12288);
        DSR(bv[7][0], bB0, 14336); DSR(bv[7][1], bB1, 14336);

        // rows 0-3 x cols 0-3 under the ladder
        WAITG(14); MQ(0, 0, 0);
        WAITG(12); MQ(1, 1, 0);
        WAITG(10); MQ(2, 2, 0);
        WAITG(8);  MQ(3, 3, 0);
        // rows 0-3 x cols 4-7 (needs bv4-7)
        WAITG(0);
        MQ(0, 0, 4); MQ(1, 1, 4); MQ(2, 2, 4); MQ(3, 3, 4);

        // ---- av rows 4-7 (registers reused; WAR safe in-order) ----
        DSR(av[0][0], aB0, 8192);   DSR(av[0][1], aB1, 8192);
        DSR(av[1][0], aB0, 10240);  DSR(av[1][1], aB1, 10240);
        DSR(av[2][0], aB0, 12288);  DSR(av[2][1], aB1, 12288);
        DSR(av[3][0], aB0, 14336);  DSR(av[3][1], aB1, 14336);
        WAITG(6); MQ(0, 4, 0); MQ(0, 4, 4);
        WAITG(4); MQ(1, 5, 0); MQ(1, 5, 4);
        WAITG(2); MQ(2, 6, 0); MQ(2, 6, 4);
        WAITG(0); MQ(3, 7, 0); MQ(3, 7, 4);

        // ---- all reads of tile t complete; restage buffer ----
        __builtin_amdgcn_s_barrier();
        const int ko1 = ((t + 1) & 63) << 6;   // wraps at t=63 (harmless)
        STAGE_A(ko1);
        STAGE_B(ko1);
        asm volatile("s_waitcnt vmcnt(0)");
        __builtin_amdgcn_s_barrier();
    }

#undef DSR
#undef WAITG
#undef MQ

    // ---- epilogue: C[row][col] = acc + bias[col]
#pragma unroll
    for (int i = 0; i < 8; ++i) {
        const int mrow = mb + wr * 128 + i * 16 + quad * 4;
#pragma unroll
        for (int j = 0; j < 8; ++j) {
            const int col = nb + j * 16 + ln;
            float* cp = C + (size_t)mrow * OUT_F + col;
#pragma unroll
            for (int r = 0; r < 4; ++r)
                cp[(size_t)r * OUT_F] = acc[i][j][r] + bj[j];
        }
    }
}

extern "C" void kernel_launch(void* const* d_in, const int* in_sizes, int n_in,
                              void* d_out, int out_size, void* d_ws, size_t ws_size,
                              hipStream_t stream) {
    const float* x = (const float*)d_in[0];       // [2,2048,4096] fp32
    const int* wq = (const int*)d_in[1];          // [NUM_GROUPS*12]
    const float* wn = (const float*)d_in[2];      // [NUM_GROUPS]
    const float* bias = (const float*)d_in[3];    // [4096]
    float* out = (float*)d_out;                   // [2,2048,4096] fp32

    u16* Wb = (u16*)d_ws;                         // 32 MB
    u16* Xb = Wb + (size_t)OUT_F * IN_F;          // 32 MB

    prep_kernel<<<16384, 256, 0, stream>>>(x, wq, wn, Wb, Xb);
    gemm_bt_kernel<<<512, 128, 0, stream>>>(Xb, Wb, bias, out);
}

// Round 12
// 161.682 us; speedup vs baseline: 3.5682x; 3.5682x over previous
//
#include <hip/hip_runtime.h>

typedef unsigned short u16;
typedef unsigned int u32;

typedef __bf16 bf16x8 __attribute__((ext_vector_type(8)));

#define OUT_F 4096
#define IN_F 4096
#define M_ROWS 4096              // 2 * 2048
#define NUM_GROUPS ((OUT_F * IN_F) / 32)   // 524288

// ---------- helpers ----------

__device__ __forceinline__ u16 f2bf(float f) {
    union { float f; u32 u; } c; c.f = f;
    u32 u = c.u;
    u += 0x7fffu + ((u >> 16) & 1u);   // round-to-nearest-even (finite inputs)
    return (u16)(u >> 16);
}

__device__ __forceinline__ u32 pk2(float a, float b) {
    return (u32)f2bf(a) | ((u32)f2bf(b) << 16);
}

__device__ __forceinline__ void async_copy16(const u16* g, u16* l) {
    __builtin_amdgcn_global_load_lds(
        (const __attribute__((address_space(1))) u32*)g,
        (__attribute__((address_space(3))) u32*)l,
        16, 0, 0);
}

__device__ __forceinline__ u32 lds_addr(const u16* p) {
    return (u32)(uintptr_t)(const __attribute__((address_space(3))) u16*)p;
}

// ---------- fused prep (unchanged) ----------
__global__ __launch_bounds__(256) void prep_kernel(
        const float* __restrict__ x, const int* __restrict__ q,
        const float* __restrict__ scales,
        u16* __restrict__ W, u16* __restrict__ Xb) {
    int bid = blockIdx.x;
    int tid = threadIdx.x;
    if (bid < 8192) {
        int t = bid * 256 + tid;
        int b0 = q[3 * t];
        int b1 = q[3 * t + 1];
        int b2 = q[3 * t + 2];
        float mv = scales[t >> 2];
        float s = mv * (2.0f / 7.0f);
        float o = -mv;

        int v0 = b0 & 7;
        int v1 = (b0 >> 3) & 7;
        int v2 = ((b0 >> 6) & 3) | ((b1 & 1) << 2);
        int v3 = (b1 >> 1) & 7;
        int v4 = (b1 >> 4) & 7;
        int v5 = ((b1 >> 7) & 1) | ((b2 & 3) << 1);
        int v6 = (b2 >> 2) & 7;
        int v7 = (b2 >> 5) & 7;
        uint4 w;
        w.x = pk2(fmaf((float)v0, s, o), fmaf((float)v1, s, o));
        w.y = pk2(fmaf((float)v2, s, o), fmaf((float)v3, s, o));
        w.z = pk2(fmaf((float)v4, s, o), fmaf((float)v5, s, o));
        w.w = pk2(fmaf((float)v6, s, o), fmaf((float)v7, s, o));
        ((uint4*)W)[t] = w;
    } else {
        int i = (bid - 8192) * 256 + tid;
        const float4* p = (const float4*)x + (size_t)i * 2;
        float4 u = p[0], v = p[1];
        uint4 w;
        w.x = pk2(u.x, u.y);
        w.y = pk2(u.z, u.w);
        w.z = pk2(v.x, v.y);
        w.w = pk2(v.z, v.w);
        ((uint4*)Xb)[i] = w;
    }
}

// ---------- 256x128 tile, 2 waves of 128x128, acc in AGPRs ----------
// C[m][n] = sum_k A[m][k]*B[n][k] + bias[n]
//
// R11 post-mortem: 128x128 wave tile needs 256 acc regs + ~140 arch regs;
// arch VGPR namespace caps at 256 -> compiler spilled to scratch (WRITE 210MB,
// 565us). R12: accumulators live in a0..a255 via inline-asm MFMA
// (v_mfma a[N:N+3], vA, vB, a[N:N+3]); arch regs ~140, unified ~400 < 450
// no-spill bound. Engages R11's traffic cut for real: 32 ds_reads/wave/K-tile
// (vs 48 in the 128x64-wave layout) -> per-CU port demand ~1500 cyc, below
// the 2484-cyc MFMA floor. Structure/addresses/ladders verbatim from R11
// (which PASSED correctness).
__global__ __launch_bounds__(128, 1) void gemm_bt_kernel(
        const u16* __restrict__ A, const u16* __restrict__ B,
        const float* __restrict__ bias, float* __restrict__ C) {
    __shared__ u16 sA[256 * 64];    // 32 KB
    __shared__ u16 sB[128 * 64];    // 16 KB

    const int tid = threadIdx.x;
    const int lane = tid & 63;
    const int wr = tid >> 6;         // wave 0..1 -> rows wr*128 + [0,128)
    const int ln = lane & 15;
    const int quad = lane >> 4;
    const int lnx = ln & 7;

    const int lin = blockIdx.x;
    const int wg = (lin & 7) * 64 + (lin >> 3);
    const int mb = (wg >> 5) * 256;   // M tile (16)
    const int nb = (wg & 31) * 128;   // N tile (32)

    // staging: pass p covers rows [p*16, p*16+16); chunk-XOR tid-only.
    const int gRow = tid >> 3;
    const int gOff0 = gRow * IN_F + (((tid & 7) ^ (gRow & 7)) * 8);
    const int ldsSlot = tid * 8;
    const u16* baseA = A + (size_t)mb * IN_F;
    const u16* baseB = B + (size_t)nb * IN_F;

    auto STAGE_A = [&](int ko) {
#pragma unroll
        for (int p = 0; p < 16; ++p)
            async_copy16(baseA + gOff0 + p * (16 * IN_F) + ko,
                         &sA[ldsSlot + p * 1024]);
    };
    auto STAGE_B = [&](int ko) {
#pragma unroll
        for (int p = 0; p < 8; ++p)
            async_copy16(baseB + gOff0 + p * (16 * IN_F) + ko,
                         &sB[ldsSlot + p * 1024]);
    };

    const u32 sAb = lds_addr(sA);
    const u32 sBb = lds_addr(sB);
    const u32 aB0 = sAb + (u32)((wr * 128 + ln) * 128 + ((quad ^ lnx) * 16));
    const u32 aB1 = sAb + (u32)((wr * 128 + ln) * 128 + (((4 + quad) ^ lnx) * 16));
    const u32 bB0 = sBb + (u32)(ln * 128 + ((quad ^ lnx) * 16));
    const u32 bB1 = sBb + (u32)(ln * 128 + (((4 + quad) ^ lnx) * 16));

    float bj[8];
#pragma unroll
    for (int j = 0; j < 8; ++j)
        bj[j] = bias[nb + j * 16 + ln];

    bf16x8 av[4][2];     // A fragments, 4 rows at a time (reused)
    bf16x8 bv[8][2];     // B fragments, all 8 col-groups live whole tile

#define Z1(n) "v_accvgpr_write_b32 a" #n ", %0\n\t"
#define Z8(a,b,c,d,e,f,g,h) Z1(a) Z1(b) Z1(c) Z1(d) Z1(e) Z1(f) Z1(g) Z1(h)
#define ACLOB8(a,b,c,d,e,f,g,h) "a" #a, "a" #b, "a" #c, "a" #d, "a" #e, "a" #f, "a" #g, "a" #h

    // ---- zero a0..a255 (also forces .agpr_count=256 via clobbers) ----
    {
        float z = 0.0f;
        asm volatile(
            Z8(0,1,2,3,4,5,6,7) Z8(8,9,10,11,12,13,14,15)
            Z8(16,17,18,19,20,21,22,23) Z8(24,25,26,27,28,29,30,31)
            Z8(32,33,34,35,36,37,38,39) Z8(40,41,42,43,44,45,46,47)
            Z8(48,49,50,51,52,53,54,55) Z8(56,57,58,59,60,61,62,63)
            Z8(64,65,66,67,68,69,70,71) Z8(72,73,74,75,76,77,78,79)
            Z8(80,81,82,83,84,85,86,87) Z8(88,89,90,91,92,93,94,95)
            Z8(96,97,98,99,100,101,102,103) Z8(104,105,106,107,108,109,110,111)
            Z8(112,113,114,115,116,117,118,119) Z8(120,121,122,123,124,125,126,127)
            Z8(128,129,130,131,132,133,134,135) Z8(136,137,138,139,140,141,142,143)
            Z8(144,145,146,147,148,149,150,151) Z8(152,153,154,155,156,157,158,159)
            Z8(160,161,162,163,164,165,166,167) Z8(168,169,170,171,172,173,174,175)
            Z8(176,177,178,179,180,181,182,183) Z8(184,185,186,187,188,189,190,191)
            Z8(192,193,194,195,196,197,198,199) Z8(200,201,202,203,204,205,206,207)
            Z8(208,209,210,211,212,213,214,215) Z8(216,217,218,219,220,221,222,223)
            Z8(224,225,226,227,228,229,230,231) Z8(232,233,234,235,236,237,238,239)
            Z8(240,241,242,243,244,245,246,247) Z8(248,249,250,251,252,253,254,255)
            :: "v"(z)
            : ACLOB8(0,1,2,3,4,5,6,7), ACLOB8(8,9,10,11,12,13,14,15),
              ACLOB8(16,17,18,19,20,21,22,23), ACLOB8(24,25,26,27,28,29,30,31),
              ACLOB8(32,33,34,35,36,37,38,39), ACLOB8(40,41,42,43,44,45,46,47),
              ACLOB8(48,49,50,51,52,53,54,55), ACLOB8(56,57,58,59,60,61,62,63),
              ACLOB8(64,65,66,67,68,69,70,71), ACLOB8(72,73,74,75,76,77,78,79),
              ACLOB8(80,81,82,83,84,85,86,87), ACLOB8(88,89,90,91,92,93,94,95),
              ACLOB8(96,97,98,99,100,101,102,103), ACLOB8(104,105,106,107,108,109,110,111),
              ACLOB8(112,113,114,115,116,117,118,119), ACLOB8(120,121,122,123,124,125,126,127),
              ACLOB8(128,129,130,131,132,133,134,135), ACLOB8(136,137,138,139,140,141,142,143),
              ACLOB8(144,145,146,147,148,149,150,151), ACLOB8(152,153,154,155,156,157,158,159),
              ACLOB8(160,161,162,163,164,165,166,167), ACLOB8(168,169,170,171,172,173,174,175),
              ACLOB8(176,177,178,179,180,181,182,183), ACLOB8(184,185,186,187,188,189,190,191),
              ACLOB8(192,193,194,195,196,197,198,199), ACLOB8(200,201,202,203,204,205,206,207),
              ACLOB8(208,209,210,211,212,213,214,215), ACLOB8(216,217,218,219,220,221,222,223),
              ACLOB8(224,225,226,227,228,229,230,231), ACLOB8(232,233,234,235,236,237,238,239),
              ACLOB8(240,241,242,243,244,245,246,247), ACLOB8(248,249,250,251,252,253,254,255));
    }
    __builtin_amdgcn_sched_barrier(0);

#define DSR(dst, base, IMM) \
    asm volatile("ds_read_b128 %0, %1 offset:" #IMM \
                 : "=v"(dst) : "v"(base))

#define WAITG(N) \
    asm volatile("s_waitcnt lgkmcnt(" #N ")"); \
    __builtin_amdgcn_sched_barrier(0);

// MFMA with AGPR accumulator range (string literal, e.g. "0:3")
#define MFA(RNG, A_, B_) \
    asm volatile("v_mfma_f32_16x16x32_bf16 a[" RNG "], %0, %1, a[" RNG "]" \
                 :: "v"(A_), "v"(B_))

// av[AI] x bv[JB..JB+3] -> acc ranges R0..R3 (kk0 sweep, then kk1; dist 4)
#define MQ(AI, JB, R0, R1, R2, R3) \
    MFA(R0, av[AI][0], bv[(JB)+0][0]); \
    MFA(R1, av[AI][0], bv[(JB)+1][0]); \
    MFA(R2, av[AI][0], bv[(JB)+2][0]); \
    MFA(R3, av[AI][0], bv[(JB)+3][0]); \
    MFA(R0, av[AI][1], bv[(JB)+0][1]); \
    MFA(R1, av[AI][1], bv[(JB)+1][1]); \
    MFA(R2, av[AI][1], bv[(JB)+2][1]); \
    MFA(R3, av[AI][1], bv[(JB)+3][1]);

    // ---- prologue: stage tile 0, drain, publish ----
    STAGE_A(0);
    STAGE_B(0);
    asm volatile("s_waitcnt vmcnt(0)");
    __builtin_amdgcn_s_barrier();

    if ((lin ^ (lin >> 8)) & 1) {
        asm volatile("s_sleep 34");
    }

#pragma unroll 1
    for (int t = 0; t < 64; ++t) {
        // ---- reads: bv0-3 (8), av rows0-3 (8), bv4-7 (8) = 24 in order ----
        DSR(bv[0][0], bB0, 0);     DSR(bv[0][1], bB1, 0);
        DSR(bv[1][0], bB0, 2048);  DSR(bv[1][1], bB1, 2048);
        DSR(bv[2][0], bB0, 4096);  DSR(bv[2][1], bB1, 4096);
        DSR(bv[3][0], bB0, 6144);  DSR(bv[3][1], bB1, 6144);
        DSR(av[0][0], aB0, 0);     DSR(av[0][1], aB1, 0);
        DSR(av[1][0], aB0, 2048);  DSR(av[1][1], aB1, 2048);
        DSR(av[2][0], aB0, 4096);  DSR(av[2][1], aB1, 4096);
        DSR(av[3][0], aB0, 6144);  DSR(av[3][1], aB1, 6144);
        DSR(bv[4][0], bB0, 8192);  DSR(bv[4][1], bB1, 8192);
        DSR(bv[5][0], bB0, 10240); DSR(bv[5][1], bB1, 10240);
        DSR(bv[6][0], bB0, 12288); DSR(bv[6][1], bB1, 12288);
        DSR(bv[7][0], bB0, 14336); DSR(bv[7][1], bB1, 14336);

        // rows 0-3 x cols 0-3 under the ladder
        WAITG(14); MQ(0, 0, "0:3", "4:7", "8:11", "12:15");
        WAITG(12); MQ(1, 0, "32:35", "36:39", "40:43", "44:47");
        WAITG(10); MQ(2, 0, "64:67", "68:71", "72:75", "76:79");
        WAITG(8);  MQ(3, 0, "96:99", "100:103", "104:107", "108:111");
        // rows 0-3 x cols 4-7 (needs bv4-7)
        WAITG(0);
        MQ(0, 4, "16:19", "20:23", "24:27", "28:31");
        MQ(1, 4, "48:51", "52:55", "56:59", "60:63");
        MQ(2, 4, "80:83", "84:87", "88:91", "92:95");
        MQ(3, 4, "112:115", "116:119", "120:123", "124:127");

        // ---- av rows 4-7 (registers reused; WAR safe in-order) ----
        DSR(av[0][0], aB0, 8192);   DSR(av[0][1], aB1, 8192);
        DSR(av[1][0], aB0, 10240);  DSR(av[1][1], aB1, 10240);
        DSR(av[2][0], aB0, 12288);  DSR(av[2][1], aB1, 12288);
        DSR(av[3][0], aB0, 14336);  DSR(av[3][1], aB1, 14336);
        WAITG(6);
        MQ(0, 0, "128:131", "132:135", "136:139", "140:143");
        MQ(0, 4, "144:147", "148:151", "152:155", "156:159");
        WAITG(4);
        MQ(1, 0, "160:163", "164:167", "168:171", "172:175");
        MQ(1, 4, "176:179", "180:183", "184:187", "188:191");
        WAITG(2);
        MQ(2, 0, "192:195", "196:199", "200:203", "204:207");
        MQ(2, 4, "208:211", "212:215", "216:219", "220:223");
        WAITG(0);
        MQ(3, 0, "224:227", "228:231", "232:235", "236:239");
        MQ(3, 4, "240:243", "244:247", "248:251", "252:255");

        // ---- all reads of tile t complete; restage buffer ----
        __builtin_amdgcn_s_barrier();
        const int ko1 = ((t + 1) & 63) << 6;   // wraps at t=63 (harmless)
        STAGE_A(ko1);
        STAGE_B(ko1);
        asm volatile("s_waitcnt vmcnt(0)");
        __builtin_amdgcn_s_barrier();
    }

#undef DSR
#undef WAITG
#undef MQ

#define RDA(n, d) asm volatile("v_accvgpr_read_b32 %0, a" #n : "=v"(d))

// epilogue block for output frag (I,J): AGPR numbers N0..N3 (literal)
#define EPI(I, J, N0, N1, N2, N3) { \
    float f0, f1, f2, f3; \
    RDA(N0, f0); RDA(N1, f1); RDA(N2, f2); RDA(N3, f3); \
    const int mrow = mb + wr * 128 + (I) * 16 + quad * 4; \
    const int col = nb + (J) * 16 + ln; \
    float* cp = C + (size_t)mrow * OUT_F + col; \
    cp[0] = f0 + bj[J]; \
    cp[(size_t)OUT_F] = f1 + bj[J]; \
    cp[2 * (size_t)OUT_F] = f2 + bj[J]; \
    cp[3 * (size_t)OUT_F] = f3 + bj[J]; }

    EPI(0, 0,   0,   1,   2,   3)  EPI(0, 1,   4,   5,   6,   7)
    EPI(0, 2,   8,   9,  10,  11)  EPI(0, 3,  12,  13,  14,  15)
    EPI(0, 4,  16,  17,  18,  19)  EPI(0, 5,  20,  21,  22,  23)
    EPI(0, 6,  24,  25,  26,  27)  EPI(0, 7,  28,  29,  30,  31)
    EPI(1, 0,  32,  33,  34,  35)  EPI(1, 1,  36,  37,  38,  39)
    EPI(1, 2,  40,  41,  42,  43)  EPI(1, 3,  44,  45,  46,  47)
    EPI(1, 4,  48,  49,  50,  51)  EPI(1, 5,  52,  53,  54,  55)
    EPI(1, 6,  56,  57,  58,  59)  EPI(1, 7,  60,  61,  62,  63)
    EPI(2, 0,  64,  65,  66,  67)  EPI(2, 1,  68,  69,  70,  71)
    EPI(2, 2,  72,  73,  74,  75)  EPI(2, 3,  76,  77,  78,  79)
    EPI(2, 4,  80,  81,  82,  83)  EPI(2, 5,  84,  85,  86,  87)
    EPI(2, 6,  88,  89,  90,  91)  EPI(2, 7,  92,  93,  94,  95)
    EPI(3, 0,  96,  97,  98,  99)  EPI(3, 1, 100, 101, 102, 103)
    EPI(3, 2, 104, 105, 106, 107)  EPI(3, 3, 108, 109, 110, 111)
    EPI(3, 4, 112, 113, 114, 115)  EPI(3, 5, 116, 117, 118, 119)
    EPI(3, 6, 120, 121, 122, 123)  EPI(3, 7, 124, 125, 126, 127)
    EPI(4, 0, 128, 129, 130, 131)  EPI(4, 1, 132, 133, 134, 135)
    EPI(4, 2, 136, 137, 138, 139)  EPI(4, 3, 140, 141, 142, 143)
    EPI(4, 4, 144, 145, 146, 147)  EPI(4, 5, 148, 149, 150, 151)
    EPI(4, 6, 152, 153, 154, 155)  EPI(4, 7, 156, 157, 158, 159)
    EPI(5, 0, 160, 161, 162, 163)  EPI(5, 1, 164, 165, 166, 167)
    EPI(5, 2, 168, 169, 170, 171)  EPI(5, 3, 172, 173, 174, 175)
    EPI(5, 4, 176, 177, 178, 179)  EPI(5, 5, 180, 181, 182, 183)
    EPI(5, 6, 184, 185, 186, 187)  EPI(5, 7, 188, 189, 190, 191)
    EPI(6, 0, 192, 193, 194, 195)  EPI(6, 1, 196, 197, 198, 199)
    EPI(6, 2, 200, 201, 202, 203)  EPI(6, 3, 204, 205, 206, 207)
    EPI(6, 4, 208, 209, 210, 211)  EPI(6, 5, 212, 213, 214, 215)
    EPI(6, 6, 216, 217, 218, 219)  EPI(6, 7, 220, 221, 222, 223)
    EPI(7, 0, 224, 225, 226, 227)  EPI(7, 1, 228, 229, 230, 231)
    EPI(7, 2, 232, 233, 234, 235)  EPI(7, 3, 236, 237, 238, 239)
    EPI(7, 4, 240, 241, 242, 243)  EPI(7, 5, 244, 245, 246, 247)
    EPI(7, 6, 248, 249, 250, 251)  EPI(7, 7, 252, 253, 254, 255)

#undef EPI
#undef RDA
#undef MFA
#undef Z1
#undef Z8
#undef ACLOB8
}

extern "C" void kernel_launch(void* const* d_in, const int* in_sizes, int n_in,
                              void* d_out, int out_size, void* d_ws, size_t ws_size,
                              hipStream_t stream) {
    const float* x = (const float*)d_in[0];       // [2,2048,4096] fp32
    const int* wq = (const int*)d_in[1];          // [NUM_GROUPS*12]
    const float* wn = (const float*)d_in[2];      // [NUM_GROUPS]
    const float* bias = (const float*)d_in[3];    // [4096]
    float* out = (float*)d_out;                   // [2,2048,4096] fp32

    u16* Wb = (u16*)d_ws;                         // 32 MB
    u16* Xb = Wb + (size_t)OUT_F * IN_F;          // 32 MB

    prep_kernel<<<16384, 256, 0, stream>>>(x, wq, wn, Wb, Xb);
    gemm_bt_kernel<<<512, 128, 0, stream>>>(Xb, Wb, bias, out);
}